// Round 1
// baseline (417.799 us; speedup 1.0000x reference)
//
#include <hip/hip_runtime.h>

// CASSI forward: out[b,l,m,n] = phi[m,n] * y2[b,m,2l+n]
//   y2[b,m,k] = sum_{l'} x[b,l',m,k-2l'] * phi[m,k-2l'],  0 <= k-2l' < N
// M=N=512, L=28, B=8, STRIDE=2, n_out = 566.
//
// R3: all x loads aligned float4 (odd-l shift via __shfl_up), float4 NT
// stores. Measured ~99 us kernel component (~4.8 TB/s of 6.3 achievable).
//
// R4 theory: every LDS access (sphi reads @4*sc, sy2 writes @4*t, sy2
// reads @2l+4t) has a 16B/lane stride -> lanes t and t+8 share a bank
// -> 8-way conflict (~2.94x serialization, m136), sitting on the FMA and
// store dependency chains. Fix: XOR bank swizzle i ^= ((i>>5)&7)<<2
// (bank bits 2-4 ^= row bits 5-7). The 8 lanes at di=32j spread to 8
// distinct banks; XOR touches only bits>=2 so v4f/v2f contiguity and
// alignment are preserved. Predicted kernel ~99 -> ~85-90 us.

#define M_DIM 512
#define N_DIM 512
#define L_DIM 28
#define B_DIM 8
#define MN_DIM (M_DIM * N_DIM)
#define NT 14      // tail quads (k = 512+4t, t<14)
#define U_DIM 14   // l-pairs (l = 2u, 2u+1)

typedef float v2f __attribute__((ext_vector_type(2)));
typedef float v4f __attribute__((ext_vector_type(4)));

// LDS bank swizzle: XOR bank bits 2-4 with row bits 5-7 (float index).
// Preserves contiguity/alignment of any run within a 4-float group.
__device__ __forceinline__ int SWZ(int i) { return i ^ (((i >> 5) & 7) << 2); }

__global__ __launch_bounds__(256) void cassi_fwd_kernel(
    const float* __restrict__ x, const float* __restrict__ phi,
    float* __restrict__ out)
{
    __shared__ __align__(16) float sphi[2][N_DIM];   // per row-half, swizzled
    __shared__ __align__(16) float sy2[2][576];      // k in [0,568), swizzled

    const int tid = threadIdx.x;
    const int r   = tid >> 7;        // row half 0/1
    const int t   = tid & 127;       // quad owner within row
    const int bm  = blockIdx.x;      // 0..2047
    const int b   = bm >> 8;
    const int m   = ((bm & 255) << 1) | r;

    const float* xrow = x + (size_t)b * L_DIM * MN_DIM + (size_t)m * N_DIM;

    // ---- Phase 1: stage phi row; keep own quad in regs for phase 3 ----
    v4f pq = *(const v4f*)(phi + (size_t)m * N_DIM + 4 * t);
    *(v4f*)&sphi[r][SWZ(4 * t)] = pq;
    __syncthreads();

    const float* sphif = &sphi[r][0];
    const bool lane0 = ((tid & 63) == 0);   // t == 0 or t == 64

    v4f acc  = {0.f, 0.f, 0.f, 0.f};
    v4f acct = {0.f, 0.f, 0.f, 0.f};

    // ---- Phase 2: for l-pair u, both l=2u (row re) and l=2u+1 (row ro)
    // read the ALIGNED quad at n = 4s, s = t-u. Even-l contributes the
    // quad directly (k = 4t+j). Odd-l needs z[4s-2..4s+1]: low half from
    // lane t-1's quad (shfl_up), high half from own quad's .xy.
#pragma unroll
    for (int u = 0; u < U_DIM; ++u) {
        const int s  = t - u;
        const int sc = s < 0 ? 0 : s;
        const float* re = xrow + (size_t)(2 * u) * MN_DIM;
        const float* ro = xrow + (size_t)(2 * u + 1) * MN_DIM;
        v4f xe = *(const v4f*)(re + 4 * sc);        // aligned 16B
        v4f xo = *(const v4f*)(ro + 4 * sc);        // aligned 16B
        v4f P  = *(const v4f*)(sphif + SWZ(4 * sc)); // phi[4s..4s+3]
        v4f ze = xe * P;
        v4f zo = xo * P;

        if (s >= 0) acc += ze;                      // l = 2u

        float lo0 = __shfl_up(zo.z, 1, 64);         // z[4s-2]
        float lo1 = __shfl_up(zo.w, 1, 64);         // z[4s-1]
        if (lane0 && s >= 1) {                      // wave boundary: t==64
            v2f xl = *(const v2f*)(ro + 4 * s - 2);
            v2f pl = *(const v2f*)(sphif + SWZ(4 * s - 2));
            lo0 = xl.x * pl.x;
            lo1 = xl.y * pl.y;
        }
        if (s >= 1) { acc.x += lo0;  acc.y += lo1; }   // l = 2u+1, j=0,1
        if (s >= 0) { acc.z += zo.x; acc.w += zo.y; }  // l = 2u+1, j=2,3

        // ---- tail quad k0 = 512+4t (threads t<14 only) ----
        if (t < NT) {
            if (u == t) {
                // only l = 2t+1 contributes: n = 510,511 -> j = 0,1
                v2f xl = *(const v2f*)(ro + 510);
                v2f pl = *(const v2f*)(sphif + SWZ(510));
                acct.x += xl.x * pl.x;
                acct.y += xl.y * pl.y;
            } else if (u > t) {
                const int n0 = 512 + 4 * t - 4 * u;  // in [460,508], aligned
                v4f xte = *(const v4f*)(re + n0);
                v4f Pt  = *(const v4f*)(sphif + SWZ(n0));
                acct += xte * Pt;                    // l = 2u
                // l = 2u+1: j=0,1 at n0-2; j=2,3 at n0
                v2f xa = *(const v2f*)(ro + n0 - 2);
                v2f pa = *(const v2f*)(sphif + SWZ(n0 - 2));
                v2f xb = *(const v2f*)(ro + n0);
                acct.x += xa.x * pa.x;
                acct.y += xa.y * pa.y;
                acct.z += xb.x * Pt.x;
                acct.w += xb.y * Pt.y;
            }
        }
    }

    *(v4f*)&sy2[r][SWZ(4 * t)] = acc;
    if (t < NT) *(v4f*)&sy2[r][SWZ(512 + 4 * t)] = acct;
    __syncthreads();

    // ---- Phase 3: out[b,l,m,4t..4t+3] = pq * y2[2l+4t..], float4 NT stores
    float* orow = out + (size_t)b * L_DIM * MN_DIM + (size_t)m * N_DIM;
    const float* sy = &sy2[r][0];
#pragma unroll
    for (int l = 0; l < L_DIM; ++l) {
        v2f ya = *(const v2f*)(sy + SWZ(2 * l + 4 * t));      // 8B-aligned
        v2f yb = *(const v2f*)(sy + SWZ(2 * l + 4 * t + 2));
        v4f o;
        o.x = pq.x * ya.x;
        o.y = pq.y * ya.y;
        o.z = pq.z * yb.x;
        o.w = pq.w * yb.y;
        __builtin_nontemporal_store(o, (v4f*)(orow + (size_t)l * MN_DIM + 4 * t));
    }
}

extern "C" void kernel_launch(void* const* d_in, const int* in_sizes, int n_in,
                              void* d_out, int out_size, void* d_ws, size_t ws_size,
                              hipStream_t stream) {
    const float* x   = (const float*)d_in[0];
    const float* phi = (const float*)d_in[1];
    float* out       = (float*)d_out;
    cassi_fwd_kernel<<<dim3(B_DIM * M_DIM / 2), dim3(256), 0, stream>>>(x, phi, out);
}

// Round 2
// 405.696 us; speedup vs baseline: 1.0298x; 1.0298x over previous
//
#include <hip/hip_runtime.h>

// CASSI forward: out[b,l,m,n] = phi[m,n] * y2[b,m,2l+n]
//   y2[b,m,k] = sum_{l'} x[b,l',m,k-2l'] * phi[m,k-2l'],  0 <= k-2l' < N
// M=N=512, L=28, B=8, STRIDE=2, n_out = 566.
//
// R4 post-mortem: LDS XOR swizzle REGRESSED (+26us). Contiguous per-lane
// b128/b64 is already conflict-free; the swizzle broke immediate-offset
// folding on every LDS access. Reverted.
//
// R5: latency/residency attack. Counters showed HBM 27%, VALU 6.5%,
// occupancy 20% -> nothing busy, latency-bound. Changes vs R3:
//  1. Split L across thread halves: block = ONE m-row, 256 threads;
//     h = tid>>7 handles u in [7h, 7h+7). Per-thread in-flight loads
//     drop 28->14 (56 data VGPRs, fits in one issue batch), per-block
//     critical path halves, grid 2048->4096 (finer packing).
//     Partial y2 in psum[2][576], reduced after a barrier.
//  2. Odd-l rows: replace __shfl_up chains (ds_bpermute ~120cy on the
//     accumulate path + divergent lane0 fixup) with an 8B-misaligned
//     dwordx4 load (HW is 4B-align capable) + ds_read_b64 of phi.

#define M_DIM 512
#define N_DIM 512
#define L_DIM 28
#define B_DIM 8
#define MN_DIM (M_DIM * N_DIM)
#define NT 14      // tail quads (k = 512+4t, t<14)
#define UH 7       // l-pairs per thread-half

typedef float v2f __attribute__((ext_vector_type(2)));
typedef float v4f __attribute__((ext_vector_type(4)));

__global__ __launch_bounds__(256) void cassi_fwd_kernel(
    const float* __restrict__ x, const float* __restrict__ phi,
    float* __restrict__ out)
{
    __shared__ __align__(16) float sphi[N_DIM];
    __shared__ __align__(16) float psum[2][576];   // partial y2 per half

    const int tid = threadIdx.x;
    const int h   = tid >> 7;        // u-half 0/1
    const int t   = tid & 127;       // quad owner within row
    const int bm  = blockIdx.x;      // 0..4095
    const int b   = bm >> 9;
    const int m   = bm & 511;

    const float* xrow = x + (size_t)b * L_DIM * MN_DIM + (size_t)m * N_DIM;

    // ---- Phase 1: stage phi row; keep own quad in regs for phase 3 ----
    v4f pq = *(const v4f*)(phi + (size_t)m * N_DIM + 4 * t);
    if (h == 0) *(v4f*)&sphi[4 * t] = pq;
    __syncthreads();

    v4f acc  = {0.f, 0.f, 0.f, 0.f};
    v4f acct = {0.f, 0.f, 0.f, 0.f};

    const int u0 = h * UH;

    // ---- Phase 2: this half's 7 l-pairs. Even l=2u: aligned quad at
    // n=4s, s=t-u. Odd l=2u+1: needs z[4s-2..4s+1] -> one misaligned
    // dwordx4 at n=4s-2 (j=0,1 use phi[4s-2..4s-1] via b64; j=2,3 use
    // P.x,P.y already in regs).
#pragma unroll
    for (int uu = 0; uu < UH; ++uu) {
        const int u  = u0 + uu;
        const int s  = t - u;
        const int ec = s < 0 ? 0 : 4 * s;            // even-row n, clamped
        const int od = 4 * s - 2;
        const int oc = od < 0 ? 0 : od;              // odd-row n, clamped
        const float* re = xrow + (size_t)(2 * u) * MN_DIM;
        const float* ro = xrow + (size_t)(2 * u + 1) * MN_DIM;

        v4f xe = *(const v4f*)(re + ec);             // aligned 16B
        v4f P  = *(const v4f*)(&sphi[ec]);           // phi[4s..4s+3]
        if (s >= 0) acc += xe * P;                   // l = 2u

        v4f xo;                                      // x[oc..oc+3], 8B-misaligned ok
        __builtin_memcpy(&xo, ro + oc, 16);
        v2f pl = *(const v2f*)(&sphi[oc]);           // phi[4s-2..4s-1] (s>=1)
        const bool ge1 = (s >= 1);
        if (ge1) {                                   // l=2u+1, j=0,1
            acc.x += xo.x * pl.x;
            acc.y += xo.y * pl.y;
        }
        float za = ge1 ? xo.z : xo.x;                // x[4s]
        float zb = ge1 ? xo.w : xo.y;                // x[4s+1]
        if (s >= 0) {                                // l=2u+1, j=2,3
            acc.z += za * P.x;
            acc.w += zb * P.y;
        }

        // ---- tail quad k0 = 512+4t (threads t<14 only) ----
        if (t < NT) {
            if (u == t) {
                // only l = 2t+1 contributes: n = 510,511 -> j = 0,1
                v2f xl  = *(const v2f*)(ro + 510);
                v2f plt = *(const v2f*)(&sphi[510]);
                acct.x += xl.x * plt.x;
                acct.y += xl.y * plt.y;
            } else if (u > t) {
                const int n0 = 512 + 4 * t - 4 * u;  // in [460,508], aligned
                v4f xte = *(const v4f*)(re + n0);
                v4f Pt  = *(const v4f*)(&sphi[n0]);
                acct += xte * Pt;                    // l = 2u
                // l = 2u+1: j=0,1 at n0-2; j=2,3 at n0
                v2f xa = *(const v2f*)(ro + n0 - 2);
                v2f pa = *(const v2f*)(&sphi[n0 - 2]);
                v2f xb = *(const v2f*)(ro + n0);
                acct.x += xa.x * pa.x;
                acct.y += xa.y * pa.y;
                acct.z += xb.x * Pt.x;
                acct.w += xb.y * Pt.y;
            }
        }
    }

    *(v4f*)&psum[h][4 * t] = acc;
    if (t < NT) *(v4f*)&psum[h][512 + 4 * t] = acct;
    __syncthreads();

    // ---- Reduce the two partial halves (in place into psum[0]) ----
    for (int i = tid; i < 568; i += 256)
        psum[0][i] += psum[1][i];
    __syncthreads();

    // ---- Phase 3: thread (h,t) stores bands l = 14h..14h+13, quad 4t ----
    float* orow = out + (size_t)b * L_DIM * MN_DIM + (size_t)m * N_DIM;
    const float* sy = &psum[0][0];
    const int l0 = h * 14;
#pragma unroll
    for (int j = 0; j < 14; ++j) {
        const int l = l0 + j;
        v2f ya = *(const v2f*)(sy + 2 * l + 4 * t);      // 8B-aligned
        v2f yb = *(const v2f*)(sy + 2 * l + 4 * t + 2);
        v4f o;
        o.x = pq.x * ya.x;
        o.y = pq.y * ya.y;
        o.z = pq.z * yb.x;
        o.w = pq.w * yb.y;
        __builtin_nontemporal_store(o, (v4f*)(orow + (size_t)l * MN_DIM + 4 * t));
    }
}

extern "C" void kernel_launch(void* const* d_in, const int* in_sizes, int n_in,
                              void* d_out, int out_size, void* d_ws, size_t ws_size,
                              hipStream_t stream) {
    const float* x   = (const float*)d_in[0];
    const float* phi = (const float*)d_in[1];
    float* out       = (float*)d_out;
    cassi_fwd_kernel<<<dim3(B_DIM * M_DIM), dim3(256), 0, stream>>>(x, phi, out);
}

// Round 3
// 393.765 us; speedup vs baseline: 1.0610x; 1.0303x over previous
//
#include <hip/hip_runtime.h>

// CASSI forward: out[b,l,m,n] = phi[m,n] * y2[b,m,2l+n]
//   y2[b,m,k] = sum_{l'} x[b,l',m,k-2l'] * phi[m,k-2l'],  0 <= k-2l' < N
// M=N=512, L=28, B=8, STRIDE=2, n_out = 566.
//
// R4 post-mortem: LDS XOR swizzle regressed (+26us) -- contiguous per-lane
// b128 is already conflict-free; swizzle broke offset folding. Reverted.
// R5 post-mortem: L-split + misaligned odd loads regressed (+14us vs R3);
// occupancy 20->73% with NO speedup => occupancy is not the limiter.
// Misaligned dwordx4 doubled line touches (FETCH 117->123MB).
//
// R6: R3's exact per-row code (all-aligned float4 x loads, odd-l shift via
// __shfl_up, float4 NT stores -- kernel ~99us, fastest so far), but block
// = 128 threads = ONE m-row = 2 waves. The __syncthreads convoy now spans
// only the waves sharing sy2; grid 2048->4096 and ~10 resident blocks/CU
// at independent phases let phase-2 read streams and phase-3 write streams
// from different blocks interleave instead of oscillating block-wide.

#define M_DIM 512
#define N_DIM 512
#define L_DIM 28
#define B_DIM 8
#define MN_DIM (M_DIM * N_DIM)
#define NT 14      // tail quads (k = 512+4t, t<14)
#define U_DIM 14   // l-pairs (l = 2u, 2u+1)

typedef float v2f __attribute__((ext_vector_type(2)));
typedef float v4f __attribute__((ext_vector_type(4)));

__global__ __launch_bounds__(128) void cassi_fwd_kernel(
    const float* __restrict__ x, const float* __restrict__ phi,
    float* __restrict__ out)
{
    __shared__ __align__(16) float sphi[N_DIM];
    __shared__ __align__(16) float sy2[576];      // k in [0,568), padded

    const int t  = threadIdx.x;      // quad owner within row, 0..127
    const int bm = blockIdx.x;       // 0..4095
    const int b  = bm >> 9;
    const int m  = bm & 511;

    const float* xrow = x + (size_t)b * L_DIM * MN_DIM + (size_t)m * N_DIM;

    // ---- Phase 1: stage phi row; keep own quad in regs for phase 3 ----
    v4f pq = *(const v4f*)(phi + (size_t)m * N_DIM + 4 * t);
    *(v4f*)&sphi[4 * t] = pq;
    __syncthreads();

    const bool lane0 = ((t & 63) == 0);   // t == 0 or t == 64

    v4f acc  = {0.f, 0.f, 0.f, 0.f};
    v4f acct = {0.f, 0.f, 0.f, 0.f};

    // ---- Phase 2: for l-pair u, both l=2u (row re) and l=2u+1 (row ro)
    // read the ALIGNED quad at n = 4s, s = t-u. Even-l contributes the
    // quad directly (k = 4t+j). Odd-l needs z[4s-2..4s+1]: low half from
    // lane t-1's quad (shfl_up), high half from own quad's .xy.
#pragma unroll
    for (int u = 0; u < U_DIM; ++u) {
        const int s  = t - u;
        const int sc = s < 0 ? 0 : s;
        const float* re = xrow + (size_t)(2 * u) * MN_DIM;
        const float* ro = xrow + (size_t)(2 * u + 1) * MN_DIM;
        v4f xe = *(const v4f*)(re + 4 * sc);        // aligned 16B
        v4f xo = *(const v4f*)(ro + 4 * sc);        // aligned 16B
        v4f P  = *(const v4f*)(&sphi[4 * sc]);      // phi[4s..4s+3]
        v4f ze = xe * P;
        v4f zo = xo * P;

        if (s >= 0) acc += ze;                      // l = 2u

        float lo0 = __shfl_up(zo.z, 1, 64);         // z[4s-2]
        float lo1 = __shfl_up(zo.w, 1, 64);         // z[4s-1]
        if (lane0 && s >= 1) {                      // wave boundary: t==64
            v2f xl = *(const v2f*)(ro + 4 * s - 2);
            v2f pl = *(const v2f*)(&sphi[4 * s - 2]);
            lo0 = xl.x * pl.x;
            lo1 = xl.y * pl.y;
        }
        if (s >= 1) { acc.x += lo0;  acc.y += lo1; }   // l = 2u+1, j=0,1
        if (s >= 0) { acc.z += zo.x; acc.w += zo.y; }  // l = 2u+1, j=2,3

        // ---- tail quad k0 = 512+4t (threads t<14 only) ----
        if (t < NT) {
            if (u == t) {
                // only l = 2t+1 contributes: n = 510,511 -> j = 0,1
                v2f xl = *(const v2f*)(ro + 510);
                v2f pl = *(const v2f*)(&sphi[510]);
                acct.x += xl.x * pl.x;
                acct.y += xl.y * pl.y;
            } else if (u > t) {
                const int n0 = 512 + 4 * t - 4 * u;  // in [460,508], aligned
                v4f xte = *(const v4f*)(re + n0);
                v4f Pt  = *(const v4f*)(&sphi[n0]);
                acct += xte * Pt;                    // l = 2u
                // l = 2u+1: j=0,1 at n0-2; j=2,3 at n0
                v2f xa = *(const v2f*)(ro + n0 - 2);
                v2f pa = *(const v2f*)(&sphi[n0 - 2]);
                v2f xb = *(const v2f*)(ro + n0);
                acct.x += xa.x * pa.x;
                acct.y += xa.y * pa.y;
                acct.z += xb.x * Pt.x;
                acct.w += xb.y * Pt.y;
            }
        }
    }

    *(v4f*)&sy2[4 * t] = acc;
    if (t < NT) *(v4f*)&sy2[512 + 4 * t] = acct;
    __syncthreads();

    // ---- Phase 3: out[b,l,m,4t..4t+3] = pq * y2[2l+4t..], float4 NT stores
    float* orow = out + (size_t)b * L_DIM * MN_DIM + (size_t)m * N_DIM;
    const float* sy = &sy2[0];
#pragma unroll
    for (int l = 0; l < L_DIM; ++l) {
        v2f ya = *(const v2f*)(sy + 2 * l + 4 * t);      // 8B-aligned
        v2f yb = *(const v2f*)(sy + 2 * l + 4 * t + 2);
        v4f o;
        o.x = pq.x * ya.x;
        o.y = pq.y * ya.y;
        o.z = pq.z * yb.x;
        o.w = pq.w * yb.y;
        __builtin_nontemporal_store(o, (v4f*)(orow + (size_t)l * MN_DIM + 4 * t));
    }
}

extern "C" void kernel_launch(void* const* d_in, const int* in_sizes, int n_in,
                              void* d_out, int out_size, void* d_ws, size_t ws_size,
                              hipStream_t stream) {
    const float* x   = (const float*)d_in[0];
    const float* phi = (const float*)d_in[1];
    float* out       = (float*)d_out;
    cassi_fwd_kernel<<<dim3(B_DIM * M_DIM), dim3(128), 0, stream>>>(x, phi, out);
}

// Round 4
// 387.329 us; speedup vs baseline: 1.0787x; 1.0166x over previous
//
#include <hip/hip_runtime.h>

// CASSI forward: out[b,l,m,n] = phi[m,n] * y2[b,m,2l+n]
//   y2[b,m,k] = sum_{l'} x[b,l',m,k-2l'] * phi[m,k-2l'],  0 <= k-2l' < N
// M=N=512, L=28, B=8, STRIDE=2, n_out = 566.
//
// History: R3 (aligned quads + shfl odd rows + NT stores) kernel ~99-104us.
// R4 LDS swizzle regressed (broke offset folding). R5 L-split regressed
// (occupancy 73% w/ no gain => not occupancy-bound). R6 one-row blocks
// neutral (=> not block-level phase-convoy-bound).
//
// R7 theory: last structural suspect is stream SCATTER: phase 3 writes
// 28 x 2KB chunks at 1MB stride per block, vs the fill's contiguous
// stream at 6.5 TB/s. Split via workspace:
//   Kernel A: R6 phases 1-2, y2 row -> ws (read-dominated, 235MB read).
//   Kernel B: block = (b, l, 8 m-rows): 16KB CONTIGUOUS NT write span;
//             reads y2 (9.4MB, L2/L3-hot) + phi (1MB, L3-hot).
// Fallback to single-kernel R6 if ws_size < 9.44 MB.

#define M_DIM 512
#define N_DIM 512
#define L_DIM 28
#define B_DIM 8
#define MN_DIM (M_DIM * N_DIM)
#define NT 14       // tail quads (k = 512+4t, t<14)
#define U_DIM 14    // l-pairs (l = 2u, 2u+1)
#define YSTRIDE 576 // ws row stride in floats (2304 B, 16B-aligned)
#define MB 8        // m-rows per kernel-B block

typedef float v2f __attribute__((ext_vector_type(2)));
typedef float v4f __attribute__((ext_vector_type(4)));

// ---------------- Kernel A: y2 = scatter-accumulate(x * phi) ----------------
__global__ __launch_bounds__(128) void cassi_y2_kernel(
    const float* __restrict__ x, const float* __restrict__ phi,
    float* __restrict__ y2w)
{
    __shared__ __align__(16) float sphi[N_DIM];

    const int t  = threadIdx.x;      // quad owner within row, 0..127
    const int bm = blockIdx.x;       // 0..4095
    const int b  = bm >> 9;
    const int m  = bm & 511;

    const float* xrow = x + (size_t)b * L_DIM * MN_DIM + (size_t)m * N_DIM;

    v4f pq = *(const v4f*)(phi + (size_t)m * N_DIM + 4 * t);
    *(v4f*)&sphi[4 * t] = pq;
    __syncthreads();

    const bool lane0 = ((t & 63) == 0);

    v4f acc  = {0.f, 0.f, 0.f, 0.f};
    v4f acct = {0.f, 0.f, 0.f, 0.f};

#pragma unroll
    for (int u = 0; u < U_DIM; ++u) {
        const int s  = t - u;
        const int sc = s < 0 ? 0 : s;
        const float* re = xrow + (size_t)(2 * u) * MN_DIM;
        const float* ro = xrow + (size_t)(2 * u + 1) * MN_DIM;
        v4f xe = *(const v4f*)(re + 4 * sc);        // aligned 16B
        v4f xo = *(const v4f*)(ro + 4 * sc);        // aligned 16B
        v4f P  = *(const v4f*)(&sphi[4 * sc]);
        v4f ze = xe * P;
        v4f zo = xo * P;

        if (s >= 0) acc += ze;                      // l = 2u

        float lo0 = __shfl_up(zo.z, 1, 64);         // z[4s-2]
        float lo1 = __shfl_up(zo.w, 1, 64);         // z[4s-1]
        if (lane0 && s >= 1) {                      // wave boundary
            v2f xl = *(const v2f*)(ro + 4 * s - 2);
            v2f pl = *(const v2f*)(&sphi[4 * s - 2]);
            lo0 = xl.x * pl.x;
            lo1 = xl.y * pl.y;
        }
        if (s >= 1) { acc.x += lo0;  acc.y += lo1; }   // l = 2u+1, j=0,1
        if (s >= 0) { acc.z += zo.x; acc.w += zo.y; }  // l = 2u+1, j=2,3

        if (t < NT) {
            if (u == t) {
                v2f xl = *(const v2f*)(ro + 510);
                v2f pl = *(const v2f*)(&sphi[510]);
                acct.x += xl.x * pl.x;
                acct.y += xl.y * pl.y;
            } else if (u > t) {
                const int n0 = 512 + 4 * t - 4 * u;  // in [460,508], aligned
                v4f xte = *(const v4f*)(re + n0);
                v4f Pt  = *(const v4f*)(&sphi[n0]);
                acct += xte * Pt;
                v2f xa = *(const v2f*)(ro + n0 - 2);
                v2f pa = *(const v2f*)(&sphi[n0 - 2]);
                v2f xb = *(const v2f*)(ro + n0);
                acct.x += xa.x * pa.x;
                acct.y += xa.y * pa.y;
                acct.z += xb.x * Pt.x;
                acct.w += xb.y * Pt.y;
            }
        }
    }

    // Normal (cached) stores: y2 is re-read by kernel B, keep it in L2/L3.
    float* yrow = y2w + (size_t)bm * YSTRIDE;
    *(v4f*)(yrow + 4 * t) = acc;
    if (t < NT) *(v4f*)(yrow + 512 + 4 * t) = acct;
}

// ------------- Kernel B: out[b,l,m,n] = phi[m,n] * y2[b,m,2l+n] -------------
// Block = (b, l, 8 consecutive m-rows): writes a contiguous 16 KB span.
__global__ __launch_bounds__(256) void cassi_expand_kernel(
    const float* __restrict__ y2w, const float* __restrict__ phi,
    float* __restrict__ out)
{
    const int bid = blockIdx.x;          // 0 .. 8*28*64-1
    const int mc  = bid & 63;            // m-chunk
    const int bl  = bid >> 6;
    const int l   = bl % L_DIM;
    const int b   = bl / L_DIM;
    const int m0  = mc * MB;

    const int c = threadIdx.x & 31;      // column group within row
    const int r = threadIdx.x >> 5;      // row 0..7
    const int m = m0 + r;

    const float* yrow = y2w + (size_t)((b << 9) | m) * YSTRIDE + 2 * l;
    const float* prow = phi + (size_t)m * N_DIM;
    float* orow = out + ((size_t)b * L_DIM + l) * MN_DIM + (size_t)m * N_DIM;

#pragma unroll
    for (int q = 0; q < 4; ++q) {
        const int n0 = 4 * c + 128 * q;              // [0,512), 16B-aligned
        v4f P  = *(const v4f*)(prow + n0);
        v2f ya = *(const v2f*)(yrow + n0);           // y2[2l+n0..+1], 8B-aligned
        v2f yb = *(const v2f*)(yrow + n0 + 2);
        v4f o;
        o.x = P.x * ya.x;
        o.y = P.y * ya.y;
        o.z = P.z * yb.x;
        o.w = P.w * yb.y;
        __builtin_nontemporal_store(o, (v4f*)(orow + n0));
    }
}

// ---------------- Fallback: proven R6 single-kernel path ----------------
__global__ __launch_bounds__(128) void cassi_fwd_kernel(
    const float* __restrict__ x, const float* __restrict__ phi,
    float* __restrict__ out)
{
    __shared__ __align__(16) float sphi[N_DIM];
    __shared__ __align__(16) float sy2[576];

    const int t  = threadIdx.x;
    const int bm = blockIdx.x;
    const int b  = bm >> 9;
    const int m  = bm & 511;

    const float* xrow = x + (size_t)b * L_DIM * MN_DIM + (size_t)m * N_DIM;

    v4f pq = *(const v4f*)(phi + (size_t)m * N_DIM + 4 * t);
    *(v4f*)&sphi[4 * t] = pq;
    __syncthreads();

    const bool lane0 = ((t & 63) == 0);
    v4f acc  = {0.f, 0.f, 0.f, 0.f};
    v4f acct = {0.f, 0.f, 0.f, 0.f};

#pragma unroll
    for (int u = 0; u < U_DIM; ++u) {
        const int s  = t - u;
        const int sc = s < 0 ? 0 : s;
        const float* re = xrow + (size_t)(2 * u) * MN_DIM;
        const float* ro = xrow + (size_t)(2 * u + 1) * MN_DIM;
        v4f xe = *(const v4f*)(re + 4 * sc);
        v4f xo = *(const v4f*)(ro + 4 * sc);
        v4f P  = *(const v4f*)(&sphi[4 * sc]);
        v4f ze = xe * P;
        v4f zo = xo * P;

        if (s >= 0) acc += ze;

        float lo0 = __shfl_up(zo.z, 1, 64);
        float lo1 = __shfl_up(zo.w, 1, 64);
        if (lane0 && s >= 1) {
            v2f xl = *(const v2f*)(ro + 4 * s - 2);
            v2f pl = *(const v2f*)(&sphi[4 * s - 2]);
            lo0 = xl.x * pl.x;
            lo1 = xl.y * pl.y;
        }
        if (s >= 1) { acc.x += lo0;  acc.y += lo1; }
        if (s >= 0) { acc.z += zo.x; acc.w += zo.y; }

        if (t < NT) {
            if (u == t) {
                v2f xl = *(const v2f*)(ro + 510);
                v2f pl = *(const v2f*)(&sphi[510]);
                acct.x += xl.x * pl.x;
                acct.y += xl.y * pl.y;
            } else if (u > t) {
                const int n0 = 512 + 4 * t - 4 * u;
                v4f xte = *(const v4f*)(re + n0);
                v4f Pt  = *(const v4f*)(&sphi[n0]);
                acct += xte * Pt;
                v2f xa = *(const v2f*)(ro + n0 - 2);
                v2f pa = *(const v2f*)(&sphi[n0 - 2]);
                v2f xb = *(const v2f*)(ro + n0);
                acct.x += xa.x * pa.x;
                acct.y += xa.y * pa.y;
                acct.z += xb.x * Pt.x;
                acct.w += xb.y * Pt.y;
            }
        }
    }

    *(v4f*)&sy2[4 * t] = acc;
    if (t < NT) *(v4f*)&sy2[512 + 4 * t] = acct;
    __syncthreads();

    float* orow = out + (size_t)b * L_DIM * MN_DIM + (size_t)m * N_DIM;
    const float* sy = &sy2[0];
#pragma unroll
    for (int l = 0; l < L_DIM; ++l) {
        v2f ya = *(const v2f*)(sy + 2 * l + 4 * t);
        v2f yb = *(const v2f*)(sy + 2 * l + 4 * t + 2);
        v4f o;
        o.x = pq.x * ya.x;
        o.y = pq.y * ya.y;
        o.z = pq.z * yb.x;
        o.w = pq.w * yb.y;
        __builtin_nontemporal_store(o, (v4f*)(orow + (size_t)l * MN_DIM + 4 * t));
    }
}

extern "C" void kernel_launch(void* const* d_in, const int* in_sizes, int n_in,
                              void* d_out, int out_size, void* d_ws, size_t ws_size,
                              hipStream_t stream) {
    const float* x   = (const float*)d_in[0];
    const float* phi = (const float*)d_in[1];
    float* out       = (float*)d_out;

    const size_t ws_needed = (size_t)B_DIM * M_DIM * YSTRIDE * sizeof(float); // 9.44 MB
    if (d_ws != nullptr && ws_size >= ws_needed) {
        float* y2w = (float*)d_ws;
        cassi_y2_kernel<<<dim3(B_DIM * M_DIM), dim3(128), 0, stream>>>(x, phi, y2w);
        cassi_expand_kernel<<<dim3(B_DIM * L_DIM * (M_DIM / MB)), dim3(256), 0, stream>>>(y2w, phi, out);
    } else {
        cassi_fwd_kernel<<<dim3(B_DIM * M_DIM), dim3(128), 0, stream>>>(x, phi, out);
    }
}